// Round 10
// baseline (189.600 us; speedup 1.0000x reference)
//
#include <hip/hip_runtime.h>
#include <hip/hip_bf16.h>
#include <hip/hip_fp8.h>

typedef __attribute__((ext_vector_type(4))) int i32x4;
typedef __attribute__((ext_vector_type(8))) int i32x8;
typedef __attribute__((ext_vector_type(16))) float f32x16;

#define MARGIN 0.3f
#define BIGF 3.0e38f

__device__ __forceinline__ f32x16 mx_mfma(i32x8 a, i32x8 b, f32x16 c) {
    return __builtin_amdgcn_mfma_scale_f32_32x32x64_f8f6f4(
        a, b, c, 0 /*A fmt fp8*/, 0 /*B fmt fp8*/,
        0, 127 /*scale A = 2^0*/, 0, 127 /*scale B = 2^0*/);
}

// 32B fragment load (one cell slice for this lane): two dwordx4.
__device__ __forceinline__ i32x8 ld32(const unsigned char* p) {
    i32x4 lo = *(const i32x4*)p;
    i32x4 hi = *(const i32x4*)(p + 16);
    return __builtin_shufflevector(lo, hi, 0, 1, 2, 3, 4, 5, 6, 7);
}

// Wave-per-row convert: fp32 -> fp8 e4m3 (OCP) cast, fp32 row norm of the
// fp8-ROUNDED values (consistent with MFMA dots -> exact diagonal), init
// ap/an/cnt. Output in FRAGMENT-NATIVE tiled layout Xf[p][t][l][32B]:
// row = p*32 + (l&31), k = t*64 + (l>>5)*32 + byte. Cell (p,t) = 2 KB
// contiguous = one wave MFMA operand fragment. (R4-verified; UNCHANGED.)
__global__ __launch_bounds__(256) void convert_norm_kernel(
    const float* __restrict__ X, unsigned char* __restrict__ Xf,
    float* __restrict__ nrm, unsigned* __restrict__ ap,
    unsigned* __restrict__ an, unsigned* __restrict__ cnt, int K) {
    const int wave = threadIdx.x >> 6, lane = threadIdx.x & 63;
    const int row = blockIdx.x * 4 + wave;
    const float* xr = X + (size_t)row * K;
    const size_t pbase = ((size_t)(row >> 5)) << 16;  // p * 65536
    const int rsub = row & 31;
    float s = 0.0f;
    for (int c = lane * 8; c < K; c += 64 * 8) {
        float4 v0 = *(const float4*)(xr + c);
        float4 v1 = *(const float4*)(xr + c + 4);
        float f[8] = {v0.x, v0.y, v0.z, v0.w, v1.x, v1.y, v1.z, v1.w};
        union { unsigned char b[8]; uint2 u; } p;
#pragma unroll
        for (int i = 0; i < 8; i++) {
            __hip_fp8_e4m3 q(f[i]);       // OCP e4m3, RNE+saturate
            p.b[i] = q.__x;
            float d = (float)q;           // decoded value
            s += d * d;
        }
        // Fragment-native address: cell (row>>5, c>>6), lane-slot
        // rsub + 32*((c>>5)&1), byte c&31 (multiple of 8 -> aligned uint2).
        const int lslot = rsub + (((c >> 5) & 1) << 5);
        unsigned char* dst = Xf + pbase + ((size_t)(c >> 6) << 11)
                             + (lslot << 5) + (c & 31);
        *(uint2*)dst = p.u;
    }
    for (int off = 32; off > 0; off >>= 1) s += __shfl_xor(s, off, 64);
    if (lane == 0) {
        nrm[row] = s;
        ap[row] = 0u;           // dist_ap >= 0 always (self is a positive)
        an[row] = 0x7F800000u;  // +inf
        if (row == 0) *cnt = 0u;
    }
}

// TRIANGULAR fp8-MX GEMM-reduce v6: 64x64 tiles, ONE WAVE per block.
// R9 post-mortem: 528 co-resident 128^2 blocks -> 16 CUs held 3 blocks
// while 240 held 2 -> duration stretched 1.45x over balanced-ideal
// (34 GB/s/CU effective vs the 50-62 envelope of R4/R5/R8). Imbalance,
// not the load path, was R9's limiter.
// v6: (1) 64x64 tiles, 2080 one-wave blocks -> max 9 / avg 8.125 per CU
// = 1.11x imbalance; same arithmetic intensity as R9 (issued bytes
// ~530 MB unchanged); zero main-loop barriers, wave owns its whole tile.
// (2) R5-proven explicit 2-deep register pipeline (best measured
// rate/byte; R9 had slipped to depth-1/VGPR-64). Regs: 64 acc + 64
// operand + ~25 addr ~= 155, no spill at launch_bounds(64,4).
// (3) Epilogue fully in-wave: row-side shfl-reduce over m-lanes +
// col-side running accumulators combined via shfl_xor(32); direct
// monotone uint atomics for both sides; no LDS reduce arrays.
// Numerics bit-identical (same per-pair k-order/MFMA as R9, which
// passed absmax 0; dual-sided emission is order-free max/min).
__global__ __launch_bounds__(64, 4) void gemm_reduce_kernel(
    const unsigned char* __restrict__ Xf, const float* __restrict__ nrm,
    const int* __restrict__ Y, unsigned* __restrict__ ap,
    unsigned* __restrict__ an, unsigned* __restrict__ cnt,
    float* __restrict__ out, int N, int K) {
    __shared__ unsigned s_done;

    const int lane = threadIdx.x;  // 64-thread block = one wave
    const int m = lane & 31;   // col within 32x32 subtile (outputs)
    const int h = lane >> 5;   // row-group (outputs)

    // Triangle unrank over 64x64 tiles: (ti,tj), tj >= ti, row-major.
    const int NB2 = N >> 6;  // 64
    int bi = blockIdx.x, ti = 0;
    while (bi >= NB2 - ti) { bi -= NB2 - ti; ti++; }
    const int tj = ti + bi;
    const int rowBase = ti << 6;
    const int colBase = tj << 6;

    f32x16 acc[2][2];
#pragma unroll
    for (int si = 0; si < 2; si++)
#pragma unroll
        for (int sj = 0; sj < 2; sj++)
#pragma unroll
            for (int rr = 0; rr < 16; rr++) acc[si][sj][rr] = 0.0f;

    // Fragment base pointers. Panel p = global_row/32 = ti*2 + si (rows),
    // tj*2 + sj (cols); cell (p,t) at p*65536 + t*2048; this lane's 32 B
    // at + lane*32.
    const unsigned char* pa[2];
    const unsigned char* pb[2];
#pragma unroll
    for (int si = 0; si < 2; si++)
        pa[si] = Xf + (((size_t)(ti * 2 + si)) << 16) + lane * 32;
#pragma unroll
    for (int sj = 0; sj < 2; sj++)
        pb[sj] = Xf + (((size_t)(tj * 2 + sj)) << 16) + lane * 32;

    i32x8 A0[2], B0[2], A1[2], B1[2];

#define LD(Ab, Bb, t)                                                   \
    do {                                                                \
        const size_t _o = (size_t)(t) << 11;                            \
        _Pragma("unroll") for (int _i = 0; _i < 2; _i++)                \
            Ab[_i] = ld32(pa[_i] + _o);                                 \
        _Pragma("unroll") for (int _j = 0; _j < 2; _j++)                \
            Bb[_j] = ld32(pb[_j] + _o);                                 \
    } while (0)

#define MM(Ab, Bb)                                                      \
    do {                                                                \
        _Pragma("unroll") for (int _i = 0; _i < 2; _i++)                \
            _Pragma("unroll") for (int _j = 0; _j < 2; _j++)            \
                acc[_i][_j] = mx_mfma(Ab[_i], Bb[_j], acc[_i][_j]);     \
    } while (0)

    const int nt = K >> 6;  // 32 k64-steps (even, >= 4)
    // R5-proven 2-deep rotation: load t+1 while computing t.
    LD(A0, B0, 0);
    int t = 0;
    for (; t + 2 < nt; t += 2) {
        LD(A1, B1, t + 1);
        MM(A0, B0);
        LD(A0, B0, t + 2);
        MM(A1, B1);
    }
    LD(A1, B1, t + 1);  // t == nt-2
    MM(A0, B0);
    MM(A1, B1);

#undef LD
#undef MM

    // Dual-sided epilogue, fully in-wave. C/D: col (within subtile) = m,
    // row64 = si*32 + (reg&3) + 8*(reg>>2) + 4*h. Col data hoisted
    // per-lane; row data broadcast loads (L1-hot).
    const int gc0 = colBase + m, gc1 = colBase + 32 + m;
    const int yc0 = Y[gc0], yc1 = Y[gc1];
    const float nc0 = nrm[gc0], nc1 = nrm[gc1];

    float cdp0 = -1.0f, cdp1 = -1.0f;
    float cdn0 = BIGF, cdn1 = BIGF;
#pragma unroll
    for (int si = 0; si < 2; si++)
#pragma unroll
        for (int reg = 0; reg < 16; reg++) {
            const int row64 = si * 32 + (reg & 3) + 8 * (reg >> 2) + 4 * h;
            const int gr = rowBase + row64;
            const int yr = Y[gr];
            const float nr = nrm[gr];
            float dp, dn;
            {   // sj = 0
                float d2 = nr + nc0 - 2.0f * acc[si][0][reg];
                float d = sqrtf(fmaxf(d2, 0.0f));
                bool same = (yr == yc0);
                float vp = same ? d : -1.0f;
                float vn = same ? BIGF : d;
                dp = vp; dn = vn;
                cdp0 = fmaxf(cdp0, vp); cdn0 = fminf(cdn0, vn);
            }
            {   // sj = 1
                float d2 = nr + nc1 - 2.0f * acc[si][1][reg];
                float d = sqrtf(fmaxf(d2, 0.0f));
                bool same = (yr == yc1);
                float vp = same ? d : -1.0f;
                float vn = same ? BIGF : d;
                dp = fmaxf(dp, vp); dn = fminf(dn, vn);
                cdp1 = fmaxf(cdp1, vp); cdn1 = fminf(cdn1, vn);
            }
            // Row-side: reduce over the 32 m-lanes (h stays fixed).
            for (int off = 1; off < 32; off <<= 1) {
                dp = fmaxf(dp, __shfl_xor(dp, off, 64));
                dn = fminf(dn, __shfl_xor(dn, off, 64));
            }
            if (m == 0) {  // lanes 0 (h=0) and 32 (h=1): disjoint row64 sets
                atomicMax(&ap[gr], __float_as_uint(fmaxf(dp, 0.0f)));
                atomicMin(&an[gr], __float_as_uint(dn));
            }
        }
    // Col-side: combine the two h-halves; h==0 lanes cover 64 cols.
    cdp0 = fmaxf(cdp0, __shfl_xor(cdp0, 32, 64));
    cdn0 = fminf(cdn0, __shfl_xor(cdn0, 32, 64));
    cdp1 = fmaxf(cdp1, __shfl_xor(cdp1, 32, 64));
    cdn1 = fminf(cdn1, __shfl_xor(cdn1, 32, 64));
    if (h == 0) {
        atomicMax(&ap[gc0], __float_as_uint(fmaxf(cdp0, 0.0f)));
        atomicMin(&an[gc0], __float_as_uint(cdn0));
        atomicMax(&ap[gc1], __float_as_uint(fmaxf(cdp1, 0.0f)));
        atomicMin(&an[gc1], __float_as_uint(cdn1));
    }

    // Last block computes the loss (release fence before counter increment;
    // acquire fence + agent-scope atomic loads in the last block).
    __syncthreads();
    if (lane == 0) {
        __threadfence();
        s_done = atomicAdd(cnt, 1u);
    }
    __syncthreads();
    if (s_done == gridDim.x - 1) {
        __threadfence();
        float s = 0.0f;
        for (int i = lane; i < N; i += 64) {
            unsigned ua = __hip_atomic_load(&ap[i], __ATOMIC_RELAXED,
                                            __HIP_MEMORY_SCOPE_AGENT);
            unsigned ub = __hip_atomic_load(&an[i], __ATOMIC_RELAXED,
                                            __HIP_MEMORY_SCOPE_AGENT);
            s += fmaxf(__uint_as_float(ua) - __uint_as_float(ub) + MARGIN, 0.0f);
        }
        for (int off = 32; off > 0; off >>= 1) s += __shfl_xor(s, off, 64);
        if (lane == 0) out[0] = s / (float)N;
    }
}

extern "C" void kernel_launch(void* const* d_in, const int* in_sizes, int n_in,
                              void* d_out, int out_size, void* d_ws, size_t ws_size,
                              hipStream_t stream) {
    const float* X = (const float*)d_in[0];
    const int* Y = (const int*)d_in[1];
    float* out = (float*)d_out;
    const int N = in_sizes[1];          // 4096
    const int K = in_sizes[0] / N;      // 2048

    char* ws = (char*)d_ws;
    unsigned char* Xf = (unsigned char*)ws;                         // N*K bytes
    float* nrm = (float*)(ws + (size_t)N * K);
    unsigned* ap = (unsigned*)((char*)nrm + (size_t)N * 4);
    unsigned* an = (unsigned*)((char*)ap + (size_t)N * 4);
    unsigned* cnt = (unsigned*)((char*)an + (size_t)N * 4);

    convert_norm_kernel<<<N / 4, 256, 0, stream>>>(X, Xf, nrm, ap, an, cnt, K);
    const int NB2 = N / 64;                        // 64
    const int ntri = NB2 * (NB2 + 1) / 2;          // 2080 triangle blocks
    gemm_reduce_kernel<<<ntri, 64, 0, stream>>>(Xf, nrm, Y, ap, an, cnt,
                                                out, N, K);
}

// Round 12
// 132.222 us; speedup vs baseline: 1.4340x; 1.4340x over previous
//
#include <hip/hip_runtime.h>
#include <hip/hip_bf16.h>
#include <hip/hip_fp8.h>

typedef __attribute__((ext_vector_type(4))) int i32x4;
typedef __attribute__((ext_vector_type(8))) int i32x8;
typedef __attribute__((ext_vector_type(16))) float f32x16;

#define MARGIN 0.3f
#define BIGF 3.0e38f

__device__ __forceinline__ f32x16 mx_mfma(i32x8 a, i32x8 b, f32x16 c) {
    return __builtin_amdgcn_mfma_scale_f32_32x32x64_f8f6f4(
        a, b, c, 0 /*A fmt fp8*/, 0 /*B fmt fp8*/,
        0, 127 /*scale A = 2^0*/, 0, 127 /*scale B = 2^0*/);
}

// 32B fragment load (one cell slice for this lane): two dwordx4.
__device__ __forceinline__ i32x8 ld32(const unsigned char* p) {
    i32x4 lo = *(const i32x4*)p;
    i32x4 hi = *(const i32x4*)(p + 16);
    return __builtin_shufflevector(lo, hi, 0, 1, 2, 3, 4, 5, 6, 7);
}

// Wave-per-row convert: fp32 -> fp8 e4m3 (OCP) cast, fp32 row norm of the
// fp8-ROUNDED values (consistent with MFMA dots -> exact diagonal), init
// ap/an/cnt. Output in FRAGMENT-NATIVE tiled layout Xf[p][t][l][32B]:
// row = p*32 + (l&31), k = t*64 + (l>>5)*32 + byte. Cell (p,t) = 2 KB
// contiguous = one wave MFMA operand fragment. (R4-verified; UNCHANGED.)
__global__ __launch_bounds__(256) void convert_norm_kernel(
    const float* __restrict__ X, unsigned char* __restrict__ Xf,
    float* __restrict__ nrm, unsigned* __restrict__ ap,
    unsigned* __restrict__ an, unsigned* __restrict__ cnt, int K) {
    const int wave = threadIdx.x >> 6, lane = threadIdx.x & 63;
    const int row = blockIdx.x * 4 + wave;
    const float* xr = X + (size_t)row * K;
    const size_t pbase = ((size_t)(row >> 5)) << 16;  // p * 65536
    const int rsub = row & 31;
    float s = 0.0f;
    for (int c = lane * 8; c < K; c += 64 * 8) {
        float4 v0 = *(const float4*)(xr + c);
        float4 v1 = *(const float4*)(xr + c + 4);
        float f[8] = {v0.x, v0.y, v0.z, v0.w, v1.x, v1.y, v1.z, v1.w};
        union { unsigned char b[8]; uint2 u; } p;
#pragma unroll
        for (int i = 0; i < 8; i++) {
            __hip_fp8_e4m3 q(f[i]);       // OCP e4m3, RNE+saturate
            p.b[i] = q.__x;
            float d = (float)q;           // decoded value
            s += d * d;
        }
        // Fragment-native address: cell (row>>5, c>>6), lane-slot
        // rsub + 32*((c>>5)&1), byte c&31 (multiple of 8 -> aligned uint2).
        const int lslot = rsub + (((c >> 5) & 1) << 5);
        unsigned char* dst = Xf + pbase + ((size_t)(c >> 6) << 11)
                             + (lslot << 5) + (c & 31);
        *(uint2*)dst = p.u;
    }
    for (int off = 32; off > 0; off >>= 1) s += __shfl_xor(s, off, 64);
    if (lane == 0) {
        nrm[row] = s;
        ap[row] = 0u;           // dist_ap >= 0 always (self is a positive)
        an[row] = 0x7F800000u;  // +inf
        if (row == 0) *cnt = 0u;
    }
}

// TRIANGULAR fp8-MX GEMM-reduce v7 (R11 resubmit; R11 was an infra
// failure, not a kernel result). R9's proven 4-wave 128^2 blocks (best
// measured per-byte engine: lockstep 2-way panel sharing, 1 KB
// L2-bytes/MFMA, ~50 GB/s/CU when balanced) + GRANULARITY FIX.
// R9's only defect: 528 co-resident blocks on 256 CUs -> 3-vs-2 tiles
// per CU -> 1.45x stretch. R10 (one-wave 64^2 blocks) proved small
// blocks kill the rate (no lockstep sharing, L1 thrash: 18 GB/s/CU).
// v7: split the LAST 16 triangle tiles into 64 quarter-tiles (64^2).
// Grid = 512 full + 64 quarter blocks; HW round-robin fill gives every
// CU 2 full blocks, quarters land as a light 3rd block on 64 CUs ->
// per-CU work 2.25 vs 2.0 tile-equivalents = 1.09x stretch (was 1.45).
// Quarter blocks keep the SAME cooperative geometry scaled down: 4
// waves 2x2 over the 64^2 tile, wave = one 32^2 subtile; unique cells
// 2A+2B per k-step for 4 MFMA = same 1 KB/MFMA intensity, lockstep
// sharing preserved. K-order t-ascending -> dot products bit-identical
// to R9 (absmax 0 proven there for triangle + dual-sided + diagonal
// redundancy; diagonal-parent quarters duplicate mirrored pairs --
// harmless for monotone max/min).
__global__ __launch_bounds__(256, 4) void gemm_reduce_kernel(
    const unsigned char* __restrict__ Xf, const float* __restrict__ nrm,
    const int* __restrict__ Y, unsigned* __restrict__ ap,
    unsigned* __restrict__ an, unsigned* __restrict__ cnt,
    float* __restrict__ out, int N, int K) {
    __shared__ int sYr[128], sYc[128];
    __shared__ float sNr[128], sNc[128];
    __shared__ float redmax[4][64], redmin[4][64];  // row-side, per wave
    __shared__ float cmax[4][64], cmin[4][64];      // col-side, per wave
    __shared__ float lsum[4];
    __shared__ unsigned s_done;

    const int tid = threadIdx.x;
    const int wave = tid >> 6;
    const int lane = tid & 63;
    const int m = lane & 31;   // col within 32x32 subtile (outputs)
    const int h = lane >> 5;   // row-group (outputs)
    const int wr = wave >> 1;  // wave row (0..1)
    const int wc = wave & 1;   // wave col (0..1)

    const int NB = N >> 7;               // 32
    const int ntri = NB * (NB + 1) / 2;  // 528
    const int FULLB = ntri - 16;         // 512 full-tile blocks
    const int nt = K >> 6;               // 32 k64-steps

    if ((int)blockIdx.x < FULLB) {
        // ---------------- FULL 128^2 TILE PATH (R9 verbatim) ----------
        int bi = blockIdx.x, ti = 0;
        while (bi >= NB - ti) { bi -= NB - ti; ti++; }
        const int tj = ti + bi;
        const int rowBase = ti << 7;
        const int colBase = tj << 7;

        if (tid < 128) {
            sYr[tid] = Y[rowBase + tid];
            sNr[tid] = nrm[rowBase + tid];
        } else {
            const int t0 = tid - 128;
            sYc[t0] = Y[colBase + t0];
            sNc[t0] = nrm[colBase + t0];
        }

        f32x16 acc[2][2];
#pragma unroll
        for (int si = 0; si < 2; si++)
#pragma unroll
            for (int sj = 0; sj < 2; sj++)
#pragma unroll
                for (int rr = 0; rr < 16; rr++) acc[si][sj][rr] = 0.0f;

        const unsigned char* pa[2];
        const unsigned char* pb[2];
#pragma unroll
        for (int si = 0; si < 2; si++)
            pa[si] = Xf + (((size_t)(rowBase >> 5) + wr * 2 + si) << 16) + lane * 32;
#pragma unroll
        for (int sj = 0; sj < 2; sj++)
            pb[sj] = Xf + (((size_t)(colBase >> 5) + wc * 2 + sj) << 16) + lane * 32;

#pragma unroll 4
        for (int t = 0; t < nt; t++) {
            const size_t off = (size_t)t << 11;
            i32x8 a0 = ld32(pa[0] + off);
            i32x8 a1 = ld32(pa[1] + off);
            i32x8 b0 = ld32(pb[0] + off);
            i32x8 b1 = ld32(pb[1] + off);
            acc[0][0] = mx_mfma(a0, b0, acc[0][0]);
            acc[0][1] = mx_mfma(a0, b1, acc[0][1]);
            acc[1][0] = mx_mfma(a1, b0, acc[1][0]);
            acc[1][1] = mx_mfma(a1, b1, acc[1][1]);
        }

        __syncthreads();  // sY/sN visible

        float cdp[2] = {-1.0f, -1.0f};
        float cdn[2] = {BIGF, BIGF};
#pragma unroll
        for (int si = 0; si < 2; si++)
#pragma unroll
            for (int reg = 0; reg < 16; reg++) {
                const int row64 = si * 32 + (reg & 3) + 8 * (reg >> 2) + 4 * h;
                const int rIdx = wr * 64 + row64;
                const int yr = sYr[rIdx];
                const float nr = sNr[rIdx];
                float dp = -1.0f, dn = BIGF;
#pragma unroll
                for (int sj = 0; sj < 2; sj++) {
                    const int cIdx = wc * 64 + sj * 32 + m;
                    float d2 = nr + sNc[cIdx] - 2.0f * acc[si][sj][reg];
                    float d = sqrtf(fmaxf(d2, 0.0f));
                    bool same = (yr == sYc[cIdx]);
                    float vp = same ? d : -1.0f;
                    float vn = same ? BIGF : d;
                    dp = fmaxf(dp, vp);
                    dn = fminf(dn, vn);
                    cdp[sj] = fmaxf(cdp[sj], vp);
                    cdn[sj] = fminf(cdn[sj], vn);
                }
                for (int off = 1; off < 32; off <<= 1) {
                    dp = fmaxf(dp, __shfl_xor(dp, off, 64));
                    dn = fminf(dn, __shfl_xor(dn, off, 64));
                }
                if (m == 0) {
                    redmax[wave][row64] = dp;
                    redmin[wave][row64] = dn;
                }
            }
#pragma unroll
        for (int sj = 0; sj < 2; sj++) {
            cdp[sj] = fmaxf(cdp[sj], __shfl_xor(cdp[sj], 32, 64));
            cdn[sj] = fminf(cdn[sj], __shfl_xor(cdn[sj], 32, 64));
            if (h == 0) {
                cmax[wave][sj * 32 + m] = cdp[sj];
                cmin[wave][sj * 32 + m] = cdn[sj];
            }
        }
        __syncthreads();

        if (tid < 128) {
            const int wr2 = tid >> 6, r64 = tid & 63;
            float mx = fmaxf(redmax[wr2 * 2][r64], redmax[wr2 * 2 + 1][r64]);
            float mn = fminf(redmin[wr2 * 2][r64], redmin[wr2 * 2 + 1][r64]);
            atomicMax(&ap[rowBase + tid], __float_as_uint(fmaxf(mx, 0.0f)));
            atomicMin(&an[rowBase + tid], __float_as_uint(mn));
        } else {
            const int t0 = tid - 128;
            const int wc2 = t0 >> 6, c64 = t0 & 63;
            float mx = fmaxf(cmax[wc2][c64], cmax[2 + wc2][c64]);
            float mn = fminf(cmin[wc2][c64], cmin[2 + wc2][c64]);
            atomicMax(&ap[colBase + t0], __float_as_uint(fmaxf(mx, 0.0f)));
            atomicMin(&an[colBase + t0], __float_as_uint(mn));
        }
    } else {
        // ---------------- QUARTER 64^2 TILE PATH ----------------------
        // qid -> parent tile FULLB + (qid>>2), quarter q: rows +(q>>1)*64,
        // cols +(q&1)*64. 4 waves 2x2 over the 64^2: wave = one 32^2
        // subtile; A panel shared by the 2 wc waves, B panel by the 2 wr
        // waves (lockstep) -> 1 KB/MFMA from L2, same as full path.
        const int qid = blockIdx.x - FULLB;
        int bi = FULLB + (qid >> 2), ti = 0;
        while (bi >= NB - ti) { bi -= NB - ti; ti++; }
        const int tj = ti + bi;
        const int q = qid & 3;
        const int rowBase = (ti << 7) + ((q >> 1) << 6);
        const int colBase = (tj << 7) + ((q & 1) << 6);

        f32x16 acc;
#pragma unroll
        for (int rr = 0; rr < 16; rr++) acc[rr] = 0.0f;

        const unsigned char* pa =
            Xf + (((size_t)(rowBase >> 5) + wr) << 16) + lane * 32;
        const unsigned char* pb =
            Xf + (((size_t)(colBase >> 5) + wc) << 16) + lane * 32;

#pragma unroll 4
        for (int t = 0; t < nt; t++) {
            const size_t off = (size_t)t << 11;
            i32x8 a = ld32(pa + off);
            i32x8 b = ld32(pb + off);
            acc = mx_mfma(a, b, acc);
        }

        // In-wave dual-sided epilogue (32^2 subtile). Col data per-lane.
        const int gc = colBase + wc * 32 + m;
        const int yc = Y[gc];
        const float nc = nrm[gc];
        float cdp = -1.0f, cdn = BIGF;
#pragma unroll
        for (int reg = 0; reg < 16; reg++) {
            const int row32 = (reg & 3) + 8 * (reg >> 2) + 4 * h;
            const int gr = rowBase + wr * 32 + row32;
            const int yr = Y[gr];
            const float nr = nrm[gr];
            float d2 = nr + nc - 2.0f * acc[reg];
            float d = sqrtf(fmaxf(d2, 0.0f));
            bool same = (yr == yc);
            float vp = same ? d : -1.0f;
            float vn = same ? BIGF : d;
            cdp = fmaxf(cdp, vp);
            cdn = fminf(cdn, vn);
            float dp = vp, dn = vn;
            for (int off = 1; off < 32; off <<= 1) {
                dp = fmaxf(dp, __shfl_xor(dp, off, 64));
                dn = fminf(dn, __shfl_xor(dn, off, 64));
            }
            if (m == 0) {  // lanes 0 (h=0) and 32 (h=1): disjoint rows
                atomicMax(&ap[gr], __float_as_uint(fmaxf(dp, 0.0f)));
                atomicMin(&an[gr], __float_as_uint(dn));
            }
        }
        // Col-side: merge the two h-halves (disjoint row sets, same col).
        cdp = fmaxf(cdp, __shfl_xor(cdp, 32, 64));
        cdn = fminf(cdn, __shfl_xor(cdn, 32, 64));
        if (h == 0) {
            atomicMax(&ap[gc], __float_as_uint(fmaxf(cdp, 0.0f)));
            atomicMin(&an[gc], __float_as_uint(cdn));
        }
    }

    // Last block computes the loss (release fence before counter increment;
    // acquire fence + agent-scope atomic loads in the last block).
    __syncthreads();
    if (tid == 0) {
        __threadfence();
        s_done = atomicAdd(cnt, 1u);
    }
    __syncthreads();
    if (s_done == gridDim.x - 1) {
        __threadfence();
        float s = 0.0f;
        for (int i = tid; i < N; i += 256) {
            unsigned ua = __hip_atomic_load(&ap[i], __ATOMIC_RELAXED,
                                            __HIP_MEMORY_SCOPE_AGENT);
            unsigned ub = __hip_atomic_load(&an[i], __ATOMIC_RELAXED,
                                            __HIP_MEMORY_SCOPE_AGENT);
            s += fmaxf(__uint_as_float(ua) - __uint_as_float(ub) + MARGIN, 0.0f);
        }
        for (int off = 32; off > 0; off >>= 1) s += __shfl_xor(s, off, 64);
        if (lane == 0) lsum[wave] = s;
        __syncthreads();
        if (tid == 0)
            out[0] = (lsum[0] + lsum[1] + lsum[2] + lsum[3]) / (float)N;
    }
}

extern "C" void kernel_launch(void* const* d_in, const int* in_sizes, int n_in,
                              void* d_out, int out_size, void* d_ws, size_t ws_size,
                              hipStream_t stream) {
    const float* X = (const float*)d_in[0];
    const int* Y = (const int*)d_in[1];
    float* out = (float*)d_out;
    const int N = in_sizes[1];          // 4096
    const int K = in_sizes[0] / N;      // 2048

    char* ws = (char*)d_ws;
    unsigned char* Xf = (unsigned char*)ws;                         // N*K bytes
    float* nrm = (float*)(ws + (size_t)N * K);
    unsigned* ap = (unsigned*)((char*)nrm + (size_t)N * 4);
    unsigned* an = (unsigned*)((char*)ap + (size_t)N * 4);
    unsigned* cnt = (unsigned*)((char*)an + (size_t)N * 4);

    convert_norm_kernel<<<N / 4, 256, 0, stream>>>(X, Xf, nrm, ap, an, cnt, K);
    const int NB = N / 128;                       // 32
    const int ntri = NB * (NB + 1) / 2;           // 528
    const int grid = (ntri - 16) + 64;            // 512 full + 64 quarter
    gemm_reduce_kernel<<<grid, 256, 0, stream>>>(Xf, nrm, Y, ap, an, cnt,
                                                 out, N, K);
}